// Round 9
// baseline (43.115 us; speedup 1.0000x reference)
//
#include <hip/hip_runtime.h>

static constexpr int NB = 4;    // batch
static constexpr int L  = 256;  // Lx == Lm
static constexpr int D  = 256;

__device__ __forceinline__ float fast_rcp(float x) {
#if __has_builtin(__builtin_amdgcn_rcpf)
    return __builtin_amdgcn_rcpf(x);
#else
    return 1.0f / x;
#endif
}

__device__ __forceinline__ float fast_exp(float x) {   // e^x
#if __has_builtin(__builtin_amdgcn_exp2f)
    return __builtin_amdgcn_exp2f(x * 1.4426950408889634f);
#else
    return __expf(x);
#endif
}

__device__ __forceinline__ float exp_2x(float x) {     // e^(2x)
#if __has_builtin(__builtin_amdgcn_exp2f)
    return __builtin_amdgcn_exp2f(x * 2.8853900817779268f);
#else
    return __expf(2.0f * x);
#endif
}

// ---------------------------------------------------------------------------
// K1: tiled GEMM for both linears; writes E = exp(2*(src@W^T+b)) in TWO
// layouts:  X-layout  EX(as float4)[d4*1024 + (b*L+row)] = E[row,4d4..4d4+3]
//           row-major ER[row*256 + col]
// Row space 0..1023 -> E1 (x,W1,b1); 1024..2047 -> E2 (mem,W2).
// ---------------------------------------------------------------------------
__global__ __launch_bounds__(256) void linear_kernel(
    const float* __restrict__ x, const float* __restrict__ mem,
    const float* __restrict__ w1, const float* __restrict__ b1,
    const float* __restrict__ w2,
    float* __restrict__ E1X, float* __restrict__ E2X,
    float* __restrict__ E1R, float* __restrict__ E2R)
{
    const int bid = blockIdx.x;           // 512: 64 rowgroups x 8 colgroups
    const int rb  = (bid >> 3) * 32;      // 0..2047
    const int cb  = (bid & 7) * 32;
    const int which = rb >= 1024;
    const int rloc  = which ? rb - 1024 : rb;   // == b*L + row
    const float* src = which ? mem : x;
    const float* W   = which ? w2  : w1;
    float* dstX = which ? E2X : E1X;
    float* dstR = which ? E2R : E1R;

    constexpr int P4 = 65;
    __shared__ __align__(16) float4 xs4[32 * P4];
    __shared__ __align__(16) float4 ws4[32 * P4];

    const int t = threadIdx.x;
    const float4* src4 = reinterpret_cast<const float4*>(src) + rloc * 64;
    const float4* Wg4  = reinterpret_cast<const float4*>(W)   + cb   * 64;
#pragma unroll
    for (int k = 0; k < 8; ++k) {
        int idx = k * 256 + t;
        int r = idx >> 6, c = idx & 63;
        xs4[r * P4 + c] = src4[r * 64 + c];
        ws4[r * P4 + c] = Wg4[r * 64 + c];
    }
    __syncthreads();

    const int rr = t >> 4, cc = t & 15;   // rows {rr, rr+16}, cols {cc, cc+16}
    const float4* a0p = xs4 + rr * P4;
    const float4* a1p = xs4 + (rr + 16) * P4;
    const float4* w0p = ws4 + cc * P4;
    const float4* w1p = ws4 + (cc + 16) * P4;
    float acc00 = 0.f, acc01 = 0.f, acc10 = 0.f, acc11 = 0.f;
#pragma unroll 4
    for (int d4 = 0; d4 < 64; ++d4) {
        float4 a0 = a0p[d4], a1 = a1p[d4];
        float4 w0 = w0p[d4], w1 = w1p[d4];
        acc00 = fmaf(a0.x, w0.x, acc00); acc00 = fmaf(a0.y, w0.y, acc00);
        acc00 = fmaf(a0.z, w0.z, acc00); acc00 = fmaf(a0.w, w0.w, acc00);
        acc01 = fmaf(a0.x, w1.x, acc01); acc01 = fmaf(a0.y, w1.y, acc01);
        acc01 = fmaf(a0.z, w1.z, acc01); acc01 = fmaf(a0.w, w1.w, acc01);
        acc10 = fmaf(a1.x, w0.x, acc10); acc10 = fmaf(a1.y, w0.y, acc10);
        acc10 = fmaf(a1.z, w0.z, acc10); acc10 = fmaf(a1.w, w0.w, acc10);
        acc11 = fmaf(a1.x, w1.x, acc11); acc11 = fmaf(a1.y, w1.y, acc11);
        acc11 = fmaf(a1.z, w1.z, acc11); acc11 = fmaf(a1.w, w1.w, acc11);
    }
    const float bias0 = which ? 0.f : b1[cb + cc];
    const float bias1 = which ? 0.f : b1[cb + cc + 16];
    const float e00 = exp_2x(acc00 + bias0);   // (rA, c0)
    const float e01 = exp_2x(acc01 + bias1);   // (rA, c1)
    const float e10 = exp_2x(acc10 + bias0);   // (rB, c0)
    const float e11 = exp_2x(acc11 + bias1);   // (rB, c1)
    const int c0 = cb + cc, c1 = cb + cc + 16;
    const int rA = rloc + rr, rB = rloc + rr + 16;
    dstX[((c0 >> 2) * 1024 + rA) * 4 + (c0 & 3)] = e00;
    dstX[((c1 >> 2) * 1024 + rA) * 4 + (c1 & 3)] = e01;
    dstX[((c0 >> 2) * 1024 + rB) * 4 + (c0 & 3)] = e10;
    dstX[((c1 >> 2) * 1024 + rB) * 4 + (c1 & 3)] = e11;
    dstR[rA * D + c0] = e00;
    dstR[rA * D + c1] = e01;
    dstR[rB * D + c0] = e10;
    dstR[rB * D + c1] = e11;
}

// ---------------------------------------------------------------------------
// K2: fused score + softmax + PV, both directions. 256 blocks, strip = 8 rows.
// XCD swizzle: bid&7 = (side<<2)|b -> each XCD owns one (side,batch) working
// set (laneE 1 MB + V 256 KB), L2-resident after first L3 pull.
//   ROW (side0): strip = 8 x-rows, lane t owns m-col t -> Smask + out
//   COL (side1): strip = 8 m-rows, lane t owns x-col t -> agg   (no ST buffer)
// term: w*rcp(fma(e_lane,e_strip,1));  S = W_tot - 2*acc.
// Max-free softmax; 1/rowsum folded into final store.
// ---------------------------------------------------------------------------
__global__ __launch_bounds__(256) void fused2_kernel(
    const float* __restrict__ x, const float* __restrict__ mem,
    const int* __restrict__ mask, const float* __restrict__ wst,
    const float* __restrict__ E1X, const float* __restrict__ E2X,
    const float* __restrict__ E1R, const float* __restrict__ E2R,
    float* __restrict__ out, float* __restrict__ Smask, float* __restrict__ agg)
{
    const int bid  = blockIdx.x;          // 256
    const int p    = bid & 7, g = bid >> 3;
    const int side = p >> 2,  b = p & 3;
    const int base = b * L;
    const int r0   = g * 8;               // x0 (ROW) or m0 (COL)
    const int t    = threadIdx.x;
    const int w    = t >> 6, l = t & 63;

    const float4* laneE  = reinterpret_cast<const float4*>(side ? E1X : E2X);
    const float4* stripR = reinterpret_cast<const float4*>(side ? E2R : E1R);

    __shared__ __align__(16) float4 sstrip[8][64];   // strip E rows
    __shared__ __align__(16) float4 swst[64];        // wst
    __shared__ __align__(16) float  sS[8][L];        // unnormalized exp(S)
    __shared__ __align__(16) float4 part[8][4][64];  // PV partials

    {   // stage strip (8 rows x 256 d) + wst, coalesced
#pragma unroll
        for (int k = 0; k < 2; ++k) {
            int idx = k * 256 + t;
            int j = idx >> 6, c = idx & 63;
            sstrip[j][c] = stripR[(base + r0 + j) * 64 + c];
        }
        if (t < 64) swst[t] = reinterpret_cast<const float4*>(wst)[t];
    }
    __syncthreads();

    // W_tot = sum(wst), redundantly per wave
    float W_tot;
    {
        float4 wv = swst[l];
        float s = (wv.x + wv.y) + (wv.z + wv.w);
#pragma unroll
        for (int o = 32; o; o >>= 1) s += __shfl_xor(s, o);
        W_tot = s;
    }

    // ---- score: acc[j] ~ S[strip-row j][lane-col t] ----
    float acc0 = 0.f, acc1 = 0.f, acc2 = 0.f, acc3 = 0.f;
    float acc4 = 0.f, acc5 = 0.f, acc6 = 0.f, acc7 = 0.f;
#pragma unroll 2
    for (int d4 = 0; d4 < 64; ++d4) {
        float4 ev = laneE[d4 * 1024 + base + t];   // coalesced per-lane (L2)
        float4 wv = swst[d4];                      // wave-uniform
#define TERM(J, ACC)                                                   \
        {   float4 sv = sstrip[J][d4];                                 \
            ACC = fmaf(wv.x, fast_rcp(fmaf(ev.x, sv.x, 1.f)), ACC);    \
            ACC = fmaf(wv.y, fast_rcp(fmaf(ev.y, sv.y, 1.f)), ACC);    \
            ACC = fmaf(wv.z, fast_rcp(fmaf(ev.z, sv.z, 1.f)), ACC);    \
            ACC = fmaf(wv.w, fast_rcp(fmaf(ev.w, sv.w, 1.f)), ACC); }
        TERM(0, acc0) TERM(1, acc1) TERM(2, acc2) TERM(3, acc3)
        TERM(4, acc4) TERM(5, acc5) TERM(6, acc6) TERM(7, acc7)
#undef TERM
    }
    float S[8];
    S[0] = fmaf(-2.f, acc0, W_tot); S[1] = fmaf(-2.f, acc1, W_tot);
    S[2] = fmaf(-2.f, acc2, W_tot); S[3] = fmaf(-2.f, acc3, W_tot);
    S[4] = fmaf(-2.f, acc4, W_tot); S[5] = fmaf(-2.f, acc5, W_tot);
    S[6] = fmaf(-2.f, acc6, W_tot); S[7] = fmaf(-2.f, acc7, W_tot);

    if (side == 0) {
        const bool dead = (mask[base + t] == 0);
#pragma unroll
        for (int j = 0; j < 8; ++j) {
            Smask[((base + r0 + j) << 8) + t] = dead ? -1e30f : S[j];
            sS[j][t] = dead ? 0.f : fast_exp(S[j]);
        }
    } else {
#pragma unroll
        for (int j = 0; j < 8; ++j) sS[j][t] = fast_exp(S[j]);
    }
    __syncthreads();

    // ---- row-sum reciprocals: wave w owns strip-rows {w, w+4} ----
    float rs0, rs1;
#pragma unroll
    for (int rr = w, it = 0; rr < 8; rr += 4, ++it) {
        float4 e4 = reinterpret_cast<const float4*>(sS[rr])[l];
        float s = (e4.x + e4.y) + (e4.z + e4.w);
#pragma unroll
        for (int o = 32; o; o >>= 1) s += __shfl_xor(s, o);
        if (it == 0) rs0 = fast_rcp(s); else rs1 = fast_rcp(s);
    }

    // ---- P @ V: wave w covers k in [64w,64w+64), lane l owns d4=l ----
    const float4* V4 = reinterpret_cast<const float4*>(side ? x : mem) + base * 64;
    float4 acc[8];
#pragma unroll
    for (int r = 0; r < 8; ++r) acc[r] = make_float4(0.f, 0.f, 0.f, 0.f);

#pragma unroll 2
    for (int k4 = 0; k4 < 16; ++k4) {
        const int m0 = w * 64 + k4 * 4;
        float4 v0 = V4[(m0 + 0) * 64 + l];
        float4 v1 = V4[(m0 + 1) * 64 + l];
        float4 v2 = V4[(m0 + 2) * 64 + l];
        float4 v3 = V4[(m0 + 3) * 64 + l];
#pragma unroll
        for (int r = 0; r < 8; ++r) {
            float4 pr = *reinterpret_cast<const float4*>(&sS[r][m0]);  // uniform b128
            acc[r].x = fmaf(pr.x, v0.x, acc[r].x); acc[r].y = fmaf(pr.x, v0.y, acc[r].y);
            acc[r].z = fmaf(pr.x, v0.z, acc[r].z); acc[r].w = fmaf(pr.x, v0.w, acc[r].w);
            acc[r].x = fmaf(pr.y, v1.x, acc[r].x); acc[r].y = fmaf(pr.y, v1.y, acc[r].y);
            acc[r].z = fmaf(pr.y, v1.z, acc[r].z); acc[r].w = fmaf(pr.y, v1.w, acc[r].w);
            acc[r].x = fmaf(pr.z, v2.x, acc[r].x); acc[r].y = fmaf(pr.z, v2.y, acc[r].y);
            acc[r].z = fmaf(pr.z, v2.z, acc[r].z); acc[r].w = fmaf(pr.z, v2.w, acc[r].w);
            acc[r].x = fmaf(pr.w, v3.x, acc[r].x); acc[r].y = fmaf(pr.w, v3.y, acc[r].y);
            acc[r].z = fmaf(pr.w, v3.z, acc[r].z); acc[r].w = fmaf(pr.w, v3.w, acc[r].w);
        }
    }
#pragma unroll
    for (int r = 0; r < 8; ++r) part[r][w][l] = acc[r];
    __syncthreads();

    // ---- reduce: wave w handles strip-rows {w, w+4}, normalize, store ----
    float* o = side ? agg : out;
#pragma unroll
    for (int rr = w, it = 0; rr < 8; rr += 4, ++it) {
        float rs = (it == 0) ? rs0 : rs1;
        float4 q0 = part[rr][0][l], q1 = part[rr][1][l];
        float4 q2 = part[rr][2][l], q3 = part[rr][3][l];
        float4 ov;
        ov.x = ((q0.x + q1.x) + (q2.x + q3.x)) * rs;
        ov.y = ((q0.y + q1.y) + (q2.y + q3.y)) * rs;
        ov.z = ((q0.z + q1.z) + (q2.z + q3.z)) * rs;
        ov.w = ((q0.w + q1.w) + (q2.w + q3.w)) * rs;
        reinterpret_cast<float4*>(o)[((base + r0 + rr) << 6) + l] = ov;
    }
}

extern "C" void kernel_launch(void* const* d_in, const int* in_sizes, int n_in,
                              void* d_out, int out_size, void* d_ws, size_t ws_size,
                              hipStream_t stream)
{
    const float* x    = (const float*)d_in[0];  // [4,256,256]
    const float* mem  = (const float*)d_in[1];  // [4,256,256]
    const int*   mask = (const int*)  d_in[2];  // [4,256]
    const float* w1   = (const float*)d_in[3];  // [256,256]
    const float* b1   = (const float*)d_in[4];  // [256]
    const float* w2   = (const float*)d_in[5];  // [256,256]
    const float* wst  = (const float*)d_in[6];  // [256]

    float* out   = (float*)d_out;               // [4,256,256]
    float* Smask = out + NB * L * L;            // [4,256,256] (masked S, output 1)
    float* agg   = Smask + NB * L * L;          // [4,256,256] (agg_2_h, output 2)

    float* E1X = (float*)d_ws;                  // 1 MiB each
    float* E2X = E1X + NB * L * D;
    float* E1R = E2X + NB * L * D;
    float* E2R = E1R + NB * L * D;

    linear_kernel<<<512, 256, 0, stream>>>(x, mem, w1, b1, w2, E1X, E2X, E1R, E2R);
    fused2_kernel<<<256, 256, 0, stream>>>(x, mem, mask, wst, E1X, E2X, E1R, E2R,
                                           out, Smask, agg);
}